// Round 1
// baseline (384.733 us; speedup 1.0000x reference)
//
#include <hip/hip_runtime.h>

typedef unsigned short u16;
typedef float  f32x4 __attribute__((ext_vector_type(4)));
typedef short  s16x8 __attribute__((ext_vector_type(8)));
typedef unsigned short u16x4 __attribute__((ext_vector_type(4)));

__device__ __forceinline__ u16 f2b(float f) {
    unsigned b = __float_as_uint(f);
    return (u16)((b + 0x7FFFu + ((b >> 16) & 1u)) >> 16);   // RNE
}
__device__ __forceinline__ float b2f(u16 u) { return __uint_as_float(((unsigned)u) << 16); }

// pi(r): bit permutation so swapped-QK^T D-layout == PV A-layout (no shuffles).
// r = kk<<5 | c<<4 | g<<2 | j  ->  kk<<5 | g<<3 | c<<2 | j
__device__ __forceinline__ int perm64(int r) {
    return (r & 0x23) | (((r >> 2) & 3) << 3) | (((r >> 4) & 1) << 2);
}

// ---------------- convert fp32 -> bf16 ----------------
__global__ __launch_bounds__(256) void cvt_f2b_k(const float* __restrict__ src, u16* __restrict__ dst, int n) {
    int i = (blockIdx.x * 256 + threadIdx.x) * 4;
    if (i < n) {
        f32x4 v = *(const f32x4*)(src + i);
        u16x4 o;
        o[0] = f2b(v[0]); o[1] = f2b(v[1]); o[2] = f2b(v[2]); o[3] = f2b(v[3]);
        *(u16x4*)(dst + i) = o;
    }
}

// ---------------- GEMM: C[m][n] = A[m][:] . W[n][:] + bias[n], K=256 ----------------
// A: [16384][256] bf16, W: [256][256] bf16 (row n dotted), out bf16.
// TRANS=1: store C^T into [4][256][4096] layout (for V). RELU=1: relu epilogue.
template<int TRANS, int RELU>
__global__ __launch_bounds__(256) void gemm_k256(const u16* __restrict__ A, const u16* __restrict__ W,
                                                 const float* __restrict__ bias, u16* __restrict__ Cd,
                                                 float scale) {
    const int tid = threadIdx.x;
    const int wv = tid >> 6, lane = tid & 63, g = lane >> 4, lq = lane & 15;
    const int m0 = blockIdx.x * 64, n0 = blockIdx.y * 64;

    const u16* arow = A + (size_t)(m0 + wv * 16 + lq) * 256;
    f32x4 acc[4];
#pragma unroll
    for (int nf = 0; nf < 4; ++nf) { acc[nf][0] = 0.f; acc[nf][1] = 0.f; acc[nf][2] = 0.f; acc[nf][3] = 0.f; }

#pragma unroll
    for (int kk = 0; kk < 8; ++kk) {
        s16x8 a = *(const s16x8*)(arow + kk * 32 + g * 8);
#pragma unroll
        for (int nf = 0; nf < 4; ++nf) {
            s16x8 b = *(const s16x8*)(W + (size_t)(n0 + nf * 16 + lq) * 256 + kk * 32 + g * 8);
            acc[nf] = __builtin_amdgcn_mfma_f32_16x16x32_bf16(a, b, acc[nf], 0, 0, 0);
        }
    }

    __shared__ __align__(16) u16 c_lds[64 * 64];
#pragma unroll
    for (int nf = 0; nf < 4; ++nf) {
        float bb = bias[n0 + nf * 16 + lq];
#pragma unroll
        for (int j = 0; j < 4; ++j) {
            float v = acc[nf][j] + bb;
            if (RELU) v = fmaxf(v, 0.f);
            v *= scale;
            if (!TRANS) c_lds[(wv * 16 + (g << 2) + j) * 64 + nf * 16 + lq] = f2b(v);
            else        c_lds[(nf * 16 + lq) * 64 + wv * 16 + (g << 2) + j] = f2b(v);
        }
    }
    __syncthreads();
    if (!TRANS) {
#pragma unroll
        for (int r = 0; r < 2; ++r) {
            int o = (r * 256 + tid) * 8, row = o >> 6, col = o & 63;
            *(s16x8*)(Cd + (size_t)(m0 + row) * 256 + n0 + col) = *(const s16x8*)(c_lds + row * 64 + col);
        }
    } else {
        int bidx = m0 >> 12, s0 = m0 & 4095;
#pragma unroll
        for (int r = 0; r < 2; ++r) {
            int o = (r * 256 + tid) * 8, drow = o >> 6, col = o & 63;
            *(s16x8*)(Cd + (size_t)bidx * 256 * 4096 + (size_t)(n0 + drow) * 4096 + s0 + col) =
                *(const s16x8*)(c_lds + drow * 64 + col);
        }
    }
}

// ---------------- flash attention ----------------
// Q,K: [4][4096][256] bf16 (q pre-scaled by 1/16). VT: [4][256][4096] bf16. O: [4][4096][256] bf16.
__global__ __launch_bounds__(256) void flash_attn(const u16* __restrict__ Q, const u16* __restrict__ K,
                                                  const u16* __restrict__ VT, u16* __restrict__ O) {
    __shared__ __align__(16) u16 smem[32768];          // 64KB: K tile 32KB + VT tile 32KB
    u16* k_lds = smem;                                  // [64][256], 16B-chunk-swizzled
    u16* v_lds = smem + 16384;                          // [256][64], 16B-chunk-swizzled

    const int tid = threadIdx.x;
    const int wv = tid >> 6, lane = tid & 63, g = lane >> 4, lq = lane & 15;
    const int bqt = blockIdx.x, b = bqt >> 6, q0 = (bqt & 63) << 6;

    const u16* qrow = Q + (size_t)(b * 4096 + q0 + wv * 16 + lq) * 256;
    s16x8 qf[8];
#pragma unroll
    for (int kk = 0; kk < 8; ++kk) qf[kk] = *(const s16x8*)(qrow + kk * 32 + g * 8);

    f32x4 acc[16];
#pragma unroll
    for (int nf = 0; nf < 16; ++nf) { acc[nf][0] = 0.f; acc[nf][1] = 0.f; acc[nf][2] = 0.f; acc[nf][3] = 0.f; }
    float m_run = -3.0e38f, l_run = 0.f;

    const u16* kbase = K + (size_t)b * 4096 * 256;
    const u16* vbase = VT + (size_t)b * 256 * 4096;

    for (int t = 0; t < 64; ++t) {
        const int kv0 = t * 64;
        // stage K tile (rows permuted by pi, chunk-swizzled)
#pragma unroll
        for (int r = 0; r < 8; ++r) {
            int o16 = r * 256 + tid;
            int row = o16 >> 5, c16 = o16 & 31;
            int prow = perm64(row);
            s16x8 val = *(const s16x8*)(kbase + (size_t)(kv0 + prow) * 256 + c16 * 8);
            *(s16x8*)(k_lds + ((row << 5) + (c16 ^ (row & 7))) * 8) = val;
        }
        // stage VT tile (chunk-swizzled)
#pragma unroll
        for (int r = 0; r < 8; ++r) {
            int o16 = r * 256 + tid;
            int row = o16 >> 3, c16 = o16 & 7;
            s16x8 val = *(const s16x8*)(vbase + (size_t)row * 4096 + kv0 + c16 * 8);
            *(s16x8*)(v_lds + ((row << 3) + (c16 ^ (row & 7))) * 8) = val;
        }
        __syncthreads();

        // ST = K . Q^T  (D-layout: lane holds S[q=lq][ki spread over f,g,j])
        f32x4 st[4];
#pragma unroll
        for (int f = 0; f < 4; ++f) { st[f][0] = 0.f; st[f][1] = 0.f; st[f][2] = 0.f; st[f][3] = 0.f; }
#pragma unroll
        for (int kk = 0; kk < 8; ++kk) {
#pragma unroll
            for (int f = 0; f < 4; ++f) {
                int row = f * 16 + lq;
                s16x8 a = *(const s16x8*)(k_lds + ((row << 5) + (((kk << 2) + g) ^ (row & 7))) * 8);
                st[f] = __builtin_amdgcn_mfma_f32_16x16x32_bf16(a, qf[kk], st[f], 0, 0, 0);
            }
        }

        // online softmax (row = lq, replicated over 4 lane-groups)
        float rm = -3.0e38f;
#pragma unroll
        for (int f = 0; f < 4; ++f)
            rm = fmaxf(rm, fmaxf(fmaxf(st[f][0], st[f][1]), fmaxf(st[f][2], st[f][3])));
        rm = fmaxf(rm, __shfl_xor(rm, 16));
        rm = fmaxf(rm, __shfl_xor(rm, 32));
        float mnew = fmaxf(m_run, rm);
        float alpha = __expf(m_run - mnew);
        float p[4][4]; float ps = 0.f;
#pragma unroll
        for (int f = 0; f < 4; ++f)
#pragma unroll
            for (int j = 0; j < 4; ++j) { float e = __expf(st[f][j] - mnew); p[f][j] = e; ps += e; }
        ps += __shfl_xor(ps, 16);
        ps += __shfl_xor(ps, 32);
        l_run = l_run * alpha + ps;
        m_run = mnew;
#pragma unroll
        for (int j = 0; j < 4; ++j) {
            float a4 = __shfl(alpha, (g << 2) + j);   // alpha of out-row 4g+j lives in lane (4g+j)
#pragma unroll
            for (int nf = 0; nf < 16; ++nf) acc[nf][j] *= a4;
        }
        // P -> bf16 A-fragments (purely local thanks to perm64 K staging)
        s16x8 pa[2];
#pragma unroll
        for (int kk = 0; kk < 2; ++kk) {
            union { s16x8 v; u16 u[8]; } pu;
#pragma unroll
            for (int j2 = 0; j2 < 4; ++j2) { pu.u[j2] = f2b(p[2 * kk][j2]); pu.u[4 + j2] = f2b(p[2 * kk + 1][j2]); }
            pa[kk] = pu.v;
        }
        // PV: acc[qi][d] += P . V
#pragma unroll
        for (int kk = 0; kk < 2; ++kk) {
#pragma unroll
            for (int nf = 0; nf < 16; ++nf) {
                int row = (nf << 4) + lq;
                s16x8 bv = *(const s16x8*)(v_lds + ((row << 3) + (((kk << 2) + g) ^ (row & 7))) * 8);
                acc[nf] = __builtin_amdgcn_mfma_f32_16x16x32_bf16(pa[kk], bv, acc[nf], 0, 0, 0);
            }
        }
        __syncthreads();
    }

    // epilogue: normalize, transpose via LDS, coalesced bf16 store
    float linv[4];
#pragma unroll
    for (int j = 0; j < 4; ++j) linv[j] = 1.0f / __shfl(l_run, (g << 2) + j);
    float* o_lds = (float*)smem;
#pragma unroll
    for (int nf = 0; nf < 16; ++nf)
#pragma unroll
        for (int j = 0; j < 4; ++j)
            o_lds[(wv * 16 + (g << 2) + j) * 256 + (nf << 4) + lq] = acc[nf][j] * linv[j];
    __syncthreads();
    u16* orow = O + (size_t)(b * 4096 + q0) * 256;
#pragma unroll
    for (int r = 0; r < 8; ++r) {
        int o = (r * 256 + tid) * 8, row = o >> 8, col = o & 255;
        const float* src = o_lds + row * 256 + col;
        union { s16x8 v; u16 u[8]; } pu;
#pragma unroll
        for (int e = 0; e < 8; ++e) pu.u[e] = f2b(src[e]);
        *(s16x8*)(orow + (size_t)row * 256 + col) = pu.v;
    }
}

// ---------------- LayerNorm(x + add) * g + b ----------------
template<int OUTF32>
__global__ __launch_bounds__(256) void ln_k(const float* __restrict__ x, const u16* __restrict__ add,
                                            const float* __restrict__ gam, const float* __restrict__ bet,
                                            float* __restrict__ outf, u16* __restrict__ outb) {
    const int row = blockIdx.x * 4 + (threadIdx.x >> 6);
    const int lane = threadIdx.x & 63;
    f32x4 xv = *(const f32x4*)(x + (size_t)row * 256 + lane * 4);
    u16x4 av = *(const u16x4*)(add + (size_t)row * 256 + lane * 4);
    float s[4];
#pragma unroll
    for (int i = 0; i < 4; ++i) s[i] = xv[i] + b2f(av[i]);
    float sum = s[0] + s[1] + s[2] + s[3];
    float sq = s[0] * s[0] + s[1] * s[1] + s[2] * s[2] + s[3] * s[3];
#pragma unroll
    for (int d = 1; d < 64; d <<= 1) { sum += __shfl_xor(sum, d); sq += __shfl_xor(sq, d); }
    float mean = sum * (1.f / 256.f);
    float var = sq * (1.f / 256.f) - mean * mean;
    float rstd = rsqrtf(var + 1e-5f);
    f32x4 gv = *(const f32x4*)(gam + lane * 4);
    f32x4 bv = *(const f32x4*)(bet + lane * 4);
    if (OUTF32) {
        f32x4 y;
#pragma unroll
        for (int i = 0; i < 4; ++i) y[i] = (s[i] - mean) * rstd * gv[i] + bv[i];
        *(f32x4*)(outf + (size_t)row * 256 + lane * 4) = y;
    } else {
        u16x4 y;
#pragma unroll
        for (int i = 0; i < 4; ++i) y[i] = f2b((s[i] - mean) * rstd * gv[i] + bv[i]);
        *(u16x4*)(outb + (size_t)row * 256 + lane * 4) = y;
    }
}

extern "C" void kernel_launch(void* const* d_in, const int* in_sizes, int n_in,
                              void* d_out, int out_size, void* d_ws, size_t ws_size,
                              hipStream_t stream) {
    const float* x   = (const float*)d_in[0];
    const float* Wq  = (const float*)d_in[1];
    const float* bq  = (const float*)d_in[2];
    const float* Wk  = (const float*)d_in[3];
    const float* bk  = (const float*)d_in[4];
    const float* Wv  = (const float*)d_in[5];
    const float* bv  = (const float*)d_in[6];
    const float* Wl  = (const float*)d_in[7];
    const float* bl  = (const float*)d_in[8];
    const float* g1  = (const float*)d_in[9];
    const float* be1 = (const float*)d_in[10];
    const float* g2  = (const float*)d_in[11];
    const float* be2 = (const float*)d_in[12];
    float* out = (float*)d_out;

    const size_t NT = 16384 * 256;       // token-matrix elements
    u16* xb  = (u16*)d_ws;               // x bf16      | later: attn-out
    u16* qb  = xb  + NT;                 // q bf16      | later: h (LN1 out)
    u16* kb  = qb  + NT;                 // k bf16      | later: h1 (relu out)
    u16* vtb = kb  + NT;                 // v^T bf16    | later: h2
    u16* wqb = vtb + NT;
    u16* wkb = wqb + 65536;
    u16* wvb = wkb + 65536;
    u16* wlb = wvb + 65536;

    cvt_f2b_k<<<4096, 256, 0, stream>>>(x, xb, 4194304);
    cvt_f2b_k<<<64, 256, 0, stream>>>(Wq, wqb, 65536);
    cvt_f2b_k<<<64, 256, 0, stream>>>(Wk, wkb, 65536);
    cvt_f2b_k<<<64, 256, 0, stream>>>(Wv, wvb, 65536);
    cvt_f2b_k<<<64, 256, 0, stream>>>(Wl, wlb, 65536);

    dim3 ggrid(256, 4);
    gemm_k256<0, 0><<<ggrid, 256, 0, stream>>>(xb, wqb, bq, qb, 0.0625f);   // q / sqrt(256)
    gemm_k256<0, 0><<<ggrid, 256, 0, stream>>>(xb, wkb, bk, kb, 1.0f);
    gemm_k256<1, 0><<<ggrid, 256, 0, stream>>>(xb, wvb, bv, vtb, 1.0f);     // v^T

    flash_attn<<<256, 256, 0, stream>>>(qb, kb, vtb, xb /* reuse as attn-out */);

    ln_k<0><<<4096, 256, 0, stream>>>(x, xb, g1, be1, nullptr, qb /* h */);

    gemm_k256<0, 1><<<ggrid, 256, 0, stream>>>(qb, wlb, bl, kb /* h1 */, 1.0f);
    gemm_k256<0, 0><<<ggrid, 256, 0, stream>>>(kb, wlb, bl, vtb /* h2 */, 1.0f);

    ln_k<1><<<4096, 256, 0, stream>>>(x, vtb, g2, be2, out, nullptr);
}

// Round 2
// 371.134 us; speedup vs baseline: 1.0366x; 1.0366x over previous
//
#include <hip/hip_runtime.h>

typedef unsigned short u16;
typedef float  f32x4 __attribute__((ext_vector_type(4)));
typedef short  s16x8 __attribute__((ext_vector_type(8)));
typedef unsigned short u16x4 __attribute__((ext_vector_type(4)));

__device__ __forceinline__ u16 f2b(float f) {
    unsigned b = __float_as_uint(f);
    return (u16)((b + 0x7FFFu + ((b >> 16) & 1u)) >> 16);   // RNE
}
__device__ __forceinline__ float b2f(u16 u) { return __uint_as_float(((unsigned)u) << 16); }

// pi(r): bit permutation so swapped-QK^T D-layout == PV A-layout (no shuffles).
// r = kk<<5 | c<<4 | g<<2 | j  ->  kk<<5 | g<<3 | c<<2 | j
__device__ __forceinline__ int perm64(int r) {
    return (r & 0x23) | (((r >> 2) & 3) << 3) | (((r >> 4) & 1) << 2);
}

// async global -> LDS, 16B per lane (dest must be linear: uniform base + lane*16)
__device__ __forceinline__ void gload16(const u16* g, u16* l) {
    __builtin_amdgcn_global_load_lds(
        (const __attribute__((address_space(1))) unsigned int*)g,
        (__attribute__((address_space(3))) unsigned int*)l,
        16, 0, 0);
}

// ---------------- convert fp32 -> bf16 ----------------
__global__ __launch_bounds__(256) void cvt_f2b_k(const float* __restrict__ src, u16* __restrict__ dst, int n) {
    int i = (blockIdx.x * 256 + threadIdx.x) * 4;
    if (i < n) {
        f32x4 v = *(const f32x4*)(src + i);
        u16x4 o;
        o[0] = f2b(v[0]); o[1] = f2b(v[1]); o[2] = f2b(v[2]); o[3] = f2b(v[3]);
        *(u16x4*)(dst + i) = o;
    }
}

// ---------------- GEMM: C[m][n] = A[m][:] . W[n][:] + bias[n], K=256 ----------------
template<int TRANS, int RELU>
__global__ __launch_bounds__(256) void gemm_k256(const u16* __restrict__ A, const u16* __restrict__ W,
                                                 const float* __restrict__ bias, u16* __restrict__ Cd,
                                                 float scale) {
    const int tid = threadIdx.x;
    const int wv = tid >> 6, lane = tid & 63, g = lane >> 4, lq = lane & 15;
    const int m0 = blockIdx.x * 64, n0 = blockIdx.y * 64;

    const u16* arow = A + (size_t)(m0 + wv * 16 + lq) * 256;
    f32x4 acc[4];
#pragma unroll
    for (int nf = 0; nf < 4; ++nf) { acc[nf][0] = 0.f; acc[nf][1] = 0.f; acc[nf][2] = 0.f; acc[nf][3] = 0.f; }

#pragma unroll
    for (int kk = 0; kk < 8; ++kk) {
        s16x8 a = *(const s16x8*)(arow + kk * 32 + g * 8);
#pragma unroll
        for (int nf = 0; nf < 4; ++nf) {
            s16x8 b = *(const s16x8*)(W + (size_t)(n0 + nf * 16 + lq) * 256 + kk * 32 + g * 8);
            acc[nf] = __builtin_amdgcn_mfma_f32_16x16x32_bf16(a, b, acc[nf], 0, 0, 0);
        }
    }

    __shared__ __align__(16) u16 c_lds[64 * 64];
#pragma unroll
    for (int nf = 0; nf < 4; ++nf) {
        float bb = bias[n0 + nf * 16 + lq];
#pragma unroll
        for (int j = 0; j < 4; ++j) {
            float v = acc[nf][j] + bb;
            if (RELU) v = fmaxf(v, 0.f);
            v *= scale;
            if (!TRANS) c_lds[(wv * 16 + (g << 2) + j) * 64 + nf * 16 + lq] = f2b(v);
            else        c_lds[(nf * 16 + lq) * 64 + wv * 16 + (g << 2) + j] = f2b(v);
        }
    }
    __syncthreads();
    if (!TRANS) {
#pragma unroll
        for (int r = 0; r < 2; ++r) {
            int o = (r * 256 + tid) * 8, row = o >> 6, col = o & 63;
            *(s16x8*)(Cd + (size_t)(m0 + row) * 256 + n0 + col) = *(const s16x8*)(c_lds + row * 64 + col);
        }
    } else {
        int bidx = m0 >> 12, s0 = m0 & 4095;
#pragma unroll
        for (int r = 0; r < 2; ++r) {
            int o = (r * 256 + tid) * 8, drow = o >> 6, col = o & 63;
            *(s16x8*)(Cd + (size_t)bidx * 256 * 4096 + (size_t)(n0 + drow) * 4096 + s0 + col) =
                *(const s16x8*)(c_lds + drow * 64 + col);
        }
    }
}

// ---------------- flash attention v2 ----------------
// QW=32 per wave, 4 waves (QBLK=128), KVBLK=64, kv-split 2, double-buffered global_load_lds.
// Q,K: [4][4096][256] bf16 (q pre-scaled by log2e/16). VT: [4][256][4096] bf16.
// Opart: [2][16384][256] bf16 (normalized partials). ml: [2][2][16384] f32 (m then l per split).
__global__ __launch_bounds__(256, 1) void flash2(const u16* __restrict__ Q, const u16* __restrict__ K,
                                                 const u16* __restrict__ VT, u16* __restrict__ Opart,
                                                 float* __restrict__ ml) {
    __shared__ __align__(16) u16 smem[65536];   // 128KB: 2 x (K 16384 + V 16384) u16
    const int tid = threadIdx.x;
    const int wv = tid >> 6, lane = tid & 63, g = lane >> 4, lqi = lane & 15;
    const int bx = blockIdx.x, s = blockIdx.y;
    const int b = bx >> 5, q0 = (bx & 31) << 7;      // 128 q-rows per block
    const int kvbase = s * 2048;                      // this block's KV half

    const u16* kb_ = K + (size_t)b * 4096 * 256;
    const u16* vb_ = VT + (size_t)b * 256 * 4096;

    // Q fragments: rows q0 + wv*32 + qh*16 + lqi
    s16x8 qf[2][8];
#pragma unroll
    for (int qh = 0; qh < 2; ++qh) {
        const u16* qrow = Q + (size_t)(b * 4096 + q0 + wv * 32 + qh * 16 + lqi) * 256;
#pragma unroll
        for (int kk = 0; kk < 8; ++kk) qf[qh][kk] = *(const s16x8*)(qrow + kk * 32 + g * 8);
    }

    // staging source offsets (u16 units), separable from the per-tile kv offset
    int koff[8], voff[8];
#pragma unroll
    for (int r = 0; r < 8; ++r) {
        int row = r * 8 + (tid >> 5), ch = tid & 31;                 // K slot
        koff[r] = perm64(row) * 256 + ((ch ^ (row & 7)) << 3);
        int vrow = r * 32 + (tid >> 3), vch = tid & 7;               // V slot
        voff[r] = vrow * 4096 + ((vch ^ (vrow & 7)) << 3);
    }

    f32x4 acc[2][16];
#pragma unroll
    for (int qh = 0; qh < 2; ++qh)
#pragma unroll
        for (int nf = 0; nf < 16; ++nf) { acc[qh][nf][0]=0.f; acc[qh][nf][1]=0.f; acc[qh][nf][2]=0.f; acc[qh][nf][3]=0.f; }
    float mrun[2] = {-1e30f, -1e30f}, lrun[2] = {0.f, 0.f};

    auto STAGE = [&](int bufsel, int t) {
        const u16* kt = kb_ + (size_t)(kvbase + (t << 6)) * 256;
        const u16* vt = vb_ + (kvbase + (t << 6));
        u16* kl = smem + bufsel * 32768 + tid * 8;
        u16* vl = kl + 16384;
#pragma unroll
        for (int r = 0; r < 8; ++r) gload16(kt + koff[r], kl + r * 2048);
#pragma unroll
        for (int r = 0; r < 8; ++r) gload16(vt + voff[r], vl + r * 2048);
    };

    auto COMPUTE = [&](int bufsel) {
        const u16* kbuf = smem + bufsel * 32768;
        const u16* vbuf = kbuf + 16384;
        // ST = K . Q^T
        f32x4 st[2][4];
#pragma unroll
        for (int qh = 0; qh < 2; ++qh)
#pragma unroll
            for (int f = 0; f < 4; ++f) { st[qh][f][0]=0.f; st[qh][f][1]=0.f; st[qh][f][2]=0.f; st[qh][f][3]=0.f; }
#pragma unroll
        for (int kk = 0; kk < 8; ++kk) {
#pragma unroll
            for (int f = 0; f < 4; ++f) {
                int row = f * 16 + lqi;
                s16x8 a = *(const s16x8*)(kbuf + ((row << 5) + (((kk << 2) + g) ^ (row & 7))) * 8);
                st[0][f] = __builtin_amdgcn_mfma_f32_16x16x32_bf16(a, qf[0][kk], st[0][f], 0, 0, 0);
                st[1][f] = __builtin_amdgcn_mfma_f32_16x16x32_bf16(a, qf[1][kk], st[1][f], 0, 0, 0);
            }
        }
        // online softmax (base-2 domain), defer-max rescale
        s16x8 pa[2][2];
#pragma unroll
        for (int qh = 0; qh < 2; ++qh) {
            float rm = -1e30f;
#pragma unroll
            for (int f = 0; f < 4; ++f)
                rm = fmaxf(rm, fmaxf(fmaxf(st[qh][f][0], st[qh][f][1]), fmaxf(st[qh][f][2], st[qh][f][3])));
            rm = fmaxf(rm, __shfl_xor(rm, 16));
            rm = fmaxf(rm, __shfl_xor(rm, 32));
            if (!__all(rm - mrun[qh] <= 8.f)) {
                float mnew = fmaxf(mrun[qh], rm);
                float alpha = exp2f(mrun[qh] - mnew);
#pragma unroll
                for (int j = 0; j < 4; ++j) {
                    float a4 = __shfl(alpha, (g << 2) + j);
#pragma unroll
                    for (int nf = 0; nf < 16; ++nf) acc[qh][nf][j] *= a4;
                }
                mrun[qh] = mnew;
                lrun[qh] *= alpha;
            }
            float ps = 0.f;
#pragma unroll
            for (int f = 0; f < 4; ++f)
#pragma unroll
                for (int j = 0; j < 4; ++j) { float e = exp2f(st[qh][f][j] - mrun[qh]); st[qh][f][j] = e; ps += e; }
            ps += __shfl_xor(ps, 16);
            ps += __shfl_xor(ps, 32);
            lrun[qh] += ps;
#pragma unroll
            for (int kk2 = 0; kk2 < 2; ++kk2) {
                union { s16x8 v; u16 u[8]; } pu;
#pragma unroll
                for (int j2 = 0; j2 < 4; ++j2) { pu.u[j2] = f2b(st[qh][2*kk2][j2]); pu.u[4+j2] = f2b(st[qh][2*kk2+1][j2]); }
                pa[qh][kk2] = pu.v;
            }
        }
        // PV
#pragma unroll
        for (int kk2 = 0; kk2 < 2; ++kk2) {
#pragma unroll
            for (int nf = 0; nf < 16; ++nf) {
                int row = (nf << 4) + lqi;
                s16x8 bv = *(const s16x8*)(vbuf + ((row << 3) + (((kk2 << 2) + g) ^ (row & 7))) * 8);
                acc[0][nf] = __builtin_amdgcn_mfma_f32_16x16x32_bf16(pa[0][kk2], bv, acc[0][nf], 0, 0, 0);
                acc[1][nf] = __builtin_amdgcn_mfma_f32_16x16x32_bf16(pa[1][kk2], bv, acc[1][nf], 0, 0, 0);
            }
        }
    };

    STAGE(0, 0);
    for (int t2 = 0; t2 < 32; t2 += 2) {
        __syncthreads();                 // drains stage loads (vmcnt) + prior LDS reads
        STAGE(1, t2 + 1);
        COMPUTE(0);
        __syncthreads();
        if (t2 + 2 < 32) STAGE(0, t2 + 2);
        COMPUTE(1);
    }

    // epilogue
    __syncthreads();
    float linv[2][4];
#pragma unroll
    for (int qh = 0; qh < 2; ++qh)
#pragma unroll
        for (int j = 0; j < 4; ++j) linv[qh][j] = 1.0f / __shfl(lrun[qh], (g << 2) + j);
    u16* o_lds = smem;   // [128][256] bf16
#pragma unroll
    for (int qh = 0; qh < 2; ++qh)
#pragma unroll
        for (int nf = 0; nf < 16; ++nf)
#pragma unroll
            for (int j = 0; j < 4; ++j)
                o_lds[(wv * 32 + qh * 16 + (g << 2) + j) * 256 + (nf << 4) + lqi] = f2b(acc[qh][nf][j] * linv[qh][j]);
    __syncthreads();
    u16* orow = Opart + (size_t)s * 4194304 + (size_t)(b * 4096 + q0) * 256;
#pragma unroll
    for (int r = 0; r < 16; ++r) {
        int o = (r * 256 + tid) * 8, row = o >> 8, col = o & 255;
        *(s16x8*)(orow + (size_t)row * 256 + col) = *(const s16x8*)(o_lds + row * 256 + col);
    }
    if (lane < 16) {
#pragma unroll
        for (int qh = 0; qh < 2; ++qh) {
            int grow = b * 4096 + q0 + wv * 32 + qh * 16 + lqi;
            ml[s * 32768 + grow]         = mrun[qh];
            ml[s * 32768 + 16384 + grow] = lrun[qh];
        }
    }
}

// ---------------- recombine the two kv-split partials ----------------
__global__ __launch_bounds__(256) void recomb_k(const u16* __restrict__ Opart, const float* __restrict__ ml,
                                                u16* __restrict__ out) {
    const int row = blockIdx.x * 4 + (threadIdx.x >> 6);
    const int lane = threadIdx.x & 63;
    float m0 = ml[row],          l0 = ml[16384 + row];
    float m1 = ml[32768 + row],  l1 = ml[49152 + row];
    float mm = fmaxf(m0, m1);
    float a0 = l0 * exp2f(m0 - mm), a1 = l1 * exp2f(m1 - mm);
    float rs = 1.0f / (a0 + a1);
    a0 *= rs; a1 *= rs;
    u16x4 v0 = *(const u16x4*)(Opart + (size_t)row * 256 + lane * 4);
    u16x4 v1 = *(const u16x4*)(Opart + 4194304 + (size_t)row * 256 + lane * 4);
    u16x4 o;
#pragma unroll
    for (int i = 0; i < 4; ++i) o[i] = f2b(a0 * b2f(v0[i]) + a1 * b2f(v1[i]));
    *(u16x4*)(out + (size_t)row * 256 + lane * 4) = o;
}

// ---------------- LayerNorm(x + add) * g + b ----------------
template<int OUTF32>
__global__ __launch_bounds__(256) void ln_k(const float* __restrict__ x, const u16* __restrict__ add,
                                            const float* __restrict__ gam, const float* __restrict__ bet,
                                            float* __restrict__ outf, u16* __restrict__ outb) {
    const int row = blockIdx.x * 4 + (threadIdx.x >> 6);
    const int lane = threadIdx.x & 63;
    f32x4 xv = *(const f32x4*)(x + (size_t)row * 256 + lane * 4);
    u16x4 av = *(const u16x4*)(add + (size_t)row * 256 + lane * 4);
    float s[4];
#pragma unroll
    for (int i = 0; i < 4; ++i) s[i] = xv[i] + b2f(av[i]);
    float sum = s[0] + s[1] + s[2] + s[3];
    float sq = s[0] * s[0] + s[1] * s[1] + s[2] * s[2] + s[3] * s[3];
#pragma unroll
    for (int d = 1; d < 64; d <<= 1) { sum += __shfl_xor(sum, d); sq += __shfl_xor(sq, d); }
    float mean = sum * (1.f / 256.f);
    float var = sq * (1.f / 256.f) - mean * mean;
    float rstd = rsqrtf(var + 1e-5f);
    f32x4 gv = *(const f32x4*)(gam + lane * 4);
    f32x4 bv = *(const f32x4*)(bet + lane * 4);
    if (OUTF32) {
        f32x4 y;
#pragma unroll
        for (int i = 0; i < 4; ++i) y[i] = (s[i] - mean) * rstd * gv[i] + bv[i];
        *(f32x4*)(outf + (size_t)row * 256 + lane * 4) = y;
    } else {
        u16x4 y;
#pragma unroll
        for (int i = 0; i < 4; ++i) y[i] = f2b((s[i] - mean) * rstd * gv[i] + bv[i]);
        *(u16x4*)(outb + (size_t)row * 256 + lane * 4) = y;
    }
}

extern "C" void kernel_launch(void* const* d_in, const int* in_sizes, int n_in,
                              void* d_out, int out_size, void* d_ws, size_t ws_size,
                              hipStream_t stream) {
    const float* x   = (const float*)d_in[0];
    const float* Wq  = (const float*)d_in[1];
    const float* bq  = (const float*)d_in[2];
    const float* Wk  = (const float*)d_in[3];
    const float* bk  = (const float*)d_in[4];
    const float* Wv  = (const float*)d_in[5];
    const float* bv  = (const float*)d_in[6];
    const float* Wl  = (const float*)d_in[7];
    const float* bl  = (const float*)d_in[8];
    const float* g1  = (const float*)d_in[9];
    const float* be1 = (const float*)d_in[10];
    const float* g2  = (const float*)d_in[11];
    const float* be2 = (const float*)d_in[12];
    float* out = (float*)d_out;

    const size_t NT = 16384 * 256;
    u16* xb  = (u16*)d_ws;               // x bf16      | later: recombined attn-out
    u16* qb  = xb  + NT;                 // q bf16      | later: h (LN1 out)
    u16* kb  = qb  + NT;                 // k bf16      | later: h1 (relu out)
    u16* vtb = kb  + NT;                 // v^T bf16    | later: h2
    u16* o01 = vtb + NT;                 // O partials [2][16384][256]
    u16* wqb = o01 + 2 * NT;
    u16* wkb = wqb + 65536;
    u16* wvb = wkb + 65536;
    u16* wlb = wvb + 65536;
    float* ml = (float*)(wlb + 65536);   // [2][2][16384]

    cvt_f2b_k<<<4096, 256, 0, stream>>>(x, xb, 4194304);
    cvt_f2b_k<<<64, 256, 0, stream>>>(Wq, wqb, 65536);
    cvt_f2b_k<<<64, 256, 0, stream>>>(Wk, wkb, 65536);
    cvt_f2b_k<<<64, 256, 0, stream>>>(Wv, wvb, 65536);
    cvt_f2b_k<<<64, 256, 0, stream>>>(Wl, wlb, 65536);

    dim3 ggrid(256, 4);
    // q scaled by (1/sqrt(256)) * log2(e)  -> softmax computed in base-2 domain
    gemm_k256<0, 0><<<ggrid, 256, 0, stream>>>(xb, wqb, bq, qb, 0.0625f * 1.44269504f);
    gemm_k256<0, 0><<<ggrid, 256, 0, stream>>>(xb, wkb, bk, kb, 1.0f);
    gemm_k256<1, 0><<<ggrid, 256, 0, stream>>>(xb, wvb, bv, vtb, 1.0f);

    flash2<<<dim3(128, 2), 256, 0, stream>>>(qb, kb, vtb, o01, ml);
    recomb_k<<<4096, 256, 0, stream>>>(o01, ml, xb /* attn-out */);

    ln_k<0><<<4096, 256, 0, stream>>>(x, xb, g1, be1, nullptr, qb /* h */);

    gemm_k256<0, 1><<<ggrid, 256, 0, stream>>>(qb, wlb, bl, kb /* h1 */, 1.0f);
    gemm_k256<0, 0><<<ggrid, 256, 0, stream>>>(kb, wlb, bl, vtb /* h2 */, 1.0f);

    ln_k<1><<<4096, 256, 0, stream>>>(x, vtb, g2, be2, out, nullptr);
}